// Round 2
// baseline (332.068 us; speedup 1.0000x reference)
//
#include <hip/hip_runtime.h>

#define NB 8192
#define NL 64
#define NH 128
#define NHO 64

typedef __bf16 bf16x8 __attribute__((ext_vector_type(8)));
typedef float f32x4 __attribute__((ext_vector_type(4)));
typedef unsigned short ushort8 __attribute__((ext_vector_type(8)));

__device__ __forceinline__ unsigned short f2bf(float f) {
  union { float f; unsigned u; } v; v.f = f;
  unsigned r = v.u + 0x7fffu + ((v.u >> 16) & 1u);
  return (unsigned short)(r >> 16);
}

// ---------------------------------------------------------------------------
// Repack W1/W2 (f32) into bf16 MFMA-B-fragment order in d_ws.
// wp1: [layer3][ntile8][kstep4][lane64][reg8] bf16 ; value = W1[l][k][n]
//   k = kstep*32 + (lane>>4)*8 + reg, n = ntile*16 + (lane&15)
// wp2: [layer3][ntile4][kstep4][lane64][reg8]
// ---------------------------------------------------------------------------
__global__ __launch_bounds__(256) void repack_w(const float* __restrict__ W1,
                                                const float* __restrict__ W2,
                                                unsigned short* __restrict__ wp1,
                                                unsigned short* __restrict__ wp2) {
  int t = blockIdx.x * 256 + threadIdx.x;
  int lane = t & 63, g = t >> 6;
  if (g < 96) {                                   // W1: 3*8*4 groups
    int layer = g >> 5, rem = g & 31, nt = rem >> 2, ks = rem & 3;
    int n = nt * 16 + (lane & 15);
    int kb = ks * 32 + (lane >> 4) * 8;
    ushort8 v;
#pragma unroll
    for (int r = 0; r < 8; ++r)
      v[r] = f2bf(W1[(layer * 128 + kb + r) * 128 + n]);
    *reinterpret_cast<ushort8*>(wp1 + ((size_t)g * 64 + lane) * 8) = v;
  } else if (g < 144) {                           // W2: 3*4*4 groups
    int g2 = g - 96;
    int layer = g2 >> 4, rem = g2 & 15, nt = rem >> 2, ks = rem & 3;
    int n = nt * 16 + (lane & 15);
    int kb = ks * 32 + (lane >> 4) * 8;
    ushort8 v;
#pragma unroll
    for (int r = 0; r < 8; ++r)
      v[r] = f2bf(W2[(layer * 128 + kb + r) * 64 + n]);
    *reinterpret_cast<ushort8*>(wp2 + ((size_t)g2 * 64 + lane) * 8) = v;
  }
}

// ---------------------------------------------------------------------------
// Fused depth-3 MLP stack, one workgroup per batch row b.
// xbuf: bf16 [64][128], XOR-swizzled (byte ^= (row&7)<<4) -> MFMA A operand
// hbuf: f32 scratch (padded ld=132 for h, ld=68 for x1)
// Output is FLOAT32 (reference returns f32).
// ---------------------------------------------------------------------------
__global__ __launch_bounds__(256) void fused_mlp(
    const float* __restrict__ hidden,
    const float* __restrict__ b1,
    const float* __restrict__ gamma,
    const float* __restrict__ beta,
    const float* __restrict__ b2,
    const unsigned short* __restrict__ wp1u,
    const unsigned short* __restrict__ wp2u,
    float* __restrict__ out) {
  __shared__ __align__(16) unsigned short xbuf[NL * NH];  // 16 KB
  __shared__ __align__(16) float hbuf[NL * 132];          // 33 KB
  __shared__ float pmaxb[4][64];
  __shared__ float x2buf[64];

  const int tid = threadIdx.x;
  const int wave = tid >> 6, lane = tid & 63;
  char* xc = reinterpret_cast<char*>(xbuf);

  // ---- stage 0: load hidden[b] (f32) -> xbuf (bf16, swizzled) ----
  const float* src = hidden + (size_t)blockIdx.x * (NL * NH);
#pragma unroll
  for (int i = 0; i < 4; ++i) {
    int f = i * 256 + tid;          // 8-element chunk id, 0..1023
    int row = f >> 4;               // 16 chunks per 128-col row
    int cb = (f & 15) * 16;         // byte column
    const float4* p = reinterpret_cast<const float4*>(src + f * 8);
    float4 a = p[0], bq = p[1];
    ushort8 v;
    v[0] = f2bf(a.x); v[1] = f2bf(a.y); v[2] = f2bf(a.z); v[3] = f2bf(a.w);
    v[4] = f2bf(bq.x); v[5] = f2bf(bq.y); v[6] = f2bf(bq.z); v[7] = f2bf(bq.w);
    *reinterpret_cast<ushort8*>(xc + row * 256 + (cb ^ ((row & 7) << 4))) = v;
  }
  __syncthreads();

  for (int layer = 0; layer < 3; ++layer) {
    // ================= GEMM1: h = x @ W1 + b1  (wave -> cols [wave*32,+32)) ==
    f32x4 acc[4][2];
#pragma unroll
    for (int mt = 0; mt < 4; ++mt) {
      acc[mt][0] = f32x4{0.f, 0.f, 0.f, 0.f};
      acc[mt][1] = f32x4{0.f, 0.f, 0.f, 0.f};
    }
    const unsigned short* wl1 = wp1u + (size_t)layer * 16384;
#pragma unroll
    for (int ks = 0; ks < 4; ++ks) {
      bf16x8 bf0 = *reinterpret_cast<const bf16x8*>(
          wl1 + (((wave * 2 + 0) * 4 + ks) * 64 + lane) * 8);
      bf16x8 bf1 = *reinterpret_cast<const bf16x8*>(
          wl1 + (((wave * 2 + 1) * 4 + ks) * 64 + lane) * 8);
#pragma unroll
      for (int mt = 0; mt < 4; ++mt) {
        int row = mt * 16 + (lane & 15);
        int cb = ks * 64 + (lane >> 4) * 16;
        bf16x8 af = *reinterpret_cast<const bf16x8*>(
            xc + row * 256 + (cb ^ ((row & 7) << 4)));
        acc[mt][0] = __builtin_amdgcn_mfma_f32_16x16x32_bf16(af, bf0, acc[mt][0], 0, 0, 0);
        acc[mt][1] = __builtin_amdgcn_mfma_f32_16x16x32_bf16(af, bf1, acc[mt][1], 0, 0, 0);
      }
    }
    float bv0 = b1[layer * 128 + wave * 32 + (lane & 15)];
    float bv1 = b1[layer * 128 + wave * 32 + 16 + (lane & 15)];
#pragma unroll
    for (int mt = 0; mt < 4; ++mt)
#pragma unroll
      for (int r = 0; r < 4; ++r) {
        int row = mt * 16 + ((lane >> 4) << 2) + r;
        hbuf[row * 132 + wave * 32 + (lane & 15)] = acc[mt][0][r] + bv0;
        hbuf[row * 132 + wave * 32 + 16 + (lane & 15)] = acc[mt][1][r] + bv1;
      }
    __syncthreads();

    // ================= LayerNorm + ReLU (wave -> rows [wave*16,+16)) ========
    {
      float2 g = *reinterpret_cast<const float2*>(gamma + layer * 128 + lane * 2);
      float2 be = *reinterpret_cast<const float2*>(beta + layer * 128 + lane * 2);
#pragma unroll
      for (int rr = 0; rr < 16; ++rr) {
        int row = wave * 16 + rr;
        float2 v = *reinterpret_cast<const float2*>(&hbuf[row * 132 + lane * 2]);
        float s = v.x + v.y;
        float sq = v.x * v.x + v.y * v.y;
#pragma unroll
        for (int o = 1; o < 64; o <<= 1) {
          s += __shfl_xor(s, o);
          sq += __shfl_xor(sq, o);
        }
        float mu = s * (1.f / 128.f);
        float var = sq * (1.f / 128.f) - mu * mu;
        float rs = rsqrtf(var + 1e-5f);
        float y0 = fmaxf((v.x - mu) * rs * g.x + be.x, 0.f);
        float y1 = fmaxf((v.y - mu) * rs * g.y + be.y, 0.f);
        unsigned pk = (unsigned)f2bf(y0) | ((unsigned)f2bf(y1) << 16);
        *reinterpret_cast<unsigned*>(
            xc + row * 256 + ((lane * 4) ^ ((row & 7) << 4))) = pk;
      }
    }
    __syncthreads();

    // ================= GEMM2: x1 = h @ W2 + b2 (wave -> cols [wave*16,+16)) =
    f32x4 acc2[4];
#pragma unroll
    for (int mt = 0; mt < 4; ++mt) acc2[mt] = f32x4{0.f, 0.f, 0.f, 0.f};
    const unsigned short* wl2 = wp2u + (size_t)layer * 8192;
#pragma unroll
    for (int ks = 0; ks < 4; ++ks) {
      bf16x8 bfr = *reinterpret_cast<const bf16x8*>(
          wl2 + ((wave * 4 + ks) * 64 + lane) * 8);
#pragma unroll
      for (int mt = 0; mt < 4; ++mt) {
        int row = mt * 16 + (lane & 15);
        int cb = ks * 64 + (lane >> 4) * 16;
        bf16x8 af = *reinterpret_cast<const bf16x8*>(
            xc + row * 256 + (cb ^ ((row & 7) << 4)));
        acc2[mt] = __builtin_amdgcn_mfma_f32_16x16x32_bf16(af, bfr, acc2[mt], 0, 0, 0);
      }
    }
    {
      float b2v = b2[layer * 64 + wave * 16 + (lane & 15)];
#pragma unroll
      for (int mt = 0; mt < 4; ++mt)
#pragma unroll
        for (int r = 0; r < 4; ++r) {
          int row = mt * 16 + ((lane >> 4) << 2) + r;
          hbuf[row * 68 + wave * 16 + (lane & 15)] = acc2[mt][r] + b2v;
        }
    }
    __syncthreads();

    // ================= max-pool over L (column max of x1 [64][64]) ==========
    {
      int c = tid & 63, chunk = tid >> 6;
      float m = -3.0e38f;
#pragma unroll
      for (int i = 0; i < 16; ++i)
        m = fmaxf(m, hbuf[(chunk * 16 + i) * 68 + c]);
      pmaxb[chunk][c] = m;
    }
    __syncthreads();
    if (tid < 64)
      x2buf[tid] = fmaxf(fmaxf(pmaxb[0][tid], pmaxb[1][tid]),
                         fmaxf(pmaxb[2][tid], pmaxb[3][tid]));
    __syncthreads();

    if (layer < 2) {
      // rebuild x = concat([x1, broadcast(x2)]) -> xbuf (bf16, swizzled)
      int row = tid >> 2, q = tid & 3;
#pragma unroll
      for (int j = 0; j < 4; ++j) {
        int col0 = q * 32 + j * 8;
        ushort8 v;
        if (col0 < 64) {
#pragma unroll
          for (int k2 = 0; k2 < 8; ++k2) v[k2] = f2bf(hbuf[row * 68 + col0 + k2]);
        } else {
#pragma unroll
          for (int k2 = 0; k2 < 8; ++k2) v[k2] = f2bf(x2buf[col0 - 64 + k2]);
        }
        *reinterpret_cast<ushort8*>(
            xc + row * 256 + ((col0 * 2) ^ ((row & 7) << 4))) = v;
      }
      __syncthreads();
    } else {
      // final output (FLOAT32): out[b] = [x2_3, x2_3]
      // (max over L of concat([x1, broadcast(max_L x1)]) == [x2, x2])
      if (tid < 128) {
        size_t o = (size_t)blockIdx.x * 128;
        out[o + tid] = x2buf[tid & 63];
      }
    }
  }
}

extern "C" void kernel_launch(void* const* d_in, const int* in_sizes, int n_in,
                              void* d_out, int out_size, void* d_ws, size_t ws_size,
                              hipStream_t stream) {
  const float* hidden = (const float*)d_in[0];
  const float* W1 = (const float*)d_in[1];
  const float* b1 = (const float*)d_in[2];
  const float* gamma = (const float*)d_in[3];
  const float* beta = (const float*)d_in[4];
  const float* W2 = (const float*)d_in[5];
  const float* b2 = (const float*)d_in[6];
  (void)in_sizes; (void)n_in; (void)out_size; (void)ws_size;

  unsigned short* wp1 = (unsigned short*)d_ws;          // 3*8*4*64*8 = 49152 ushorts
  unsigned short* wp2 = wp1 + 3 * 8 * 4 * 64 * 8;       // 3*4*4*64*8 = 24576 ushorts
  float* out = (float*)d_out;

  repack_w<<<36, 256, 0, stream>>>(W1, W2, wp1, wp2);
  fused_mlp<<<NB, 256, 0, stream>>>(hidden, b1, gamma, beta, b2, wp1, wp2, out);
}

// Round 3
// 177.545 us; speedup vs baseline: 1.8703x; 1.8703x over previous
//
#include <hip/hip_runtime.h>

#define NB 8192
#define NL 64
#define NH 128

typedef __bf16 bf16x8 __attribute__((ext_vector_type(8)));
typedef float f32x4 __attribute__((ext_vector_type(4)));
typedef unsigned short ushort8 __attribute__((ext_vector_type(8)));

// phys -> logical permutation of the hidden dim (within each 32-col wave slice):
// phys p = w*32 + ci*2 + half  holds logical  w*32 + half*16 + ci
__device__ __forceinline__ int p2l(int p) {
  return (p & ~31) + ((p & 1) << 4) + ((p & 31) >> 1);
}

__device__ __forceinline__ unsigned pk2(float lo, float hi) {
  union { __bf16 b[2]; unsigned u; } t;
  t.b[0] = (__bf16)lo; t.b[1] = (__bf16)hi;
  return t.u;
}

// ---------------------------------------------------------------------------
// Repack weights (f32 -> bf16 MFMA-B fragments) + permuted gamma/beta tables.
// wp1: [layer3][ntile8][kstep4][lane64][reg8]; value = W1[l][k][n] (natural)
// wp2: [layer3][ntile4][kstep4][lane64][reg8]; value = W2[l][p2l(k)][n]
// gbt: [layer3][2(gamma,beta)][128] f32, permuted: gbt[l][p][i]=src[l][p2l(i)]
// ---------------------------------------------------------------------------
__global__ __launch_bounds__(256) void repack_w(const float* __restrict__ W1,
                                                const float* __restrict__ W2,
                                                const float* __restrict__ gamma,
                                                const float* __restrict__ beta,
                                                unsigned short* __restrict__ wp1,
                                                unsigned short* __restrict__ wp2,
                                                float* __restrict__ gbt) {
  int t = blockIdx.x * 256 + threadIdx.x;
  int lane = t & 63, g = t >> 6;
  if (g < 96) {                                   // W1: 3*8*4 groups
    int layer = g >> 5, rem = g & 31, nt = rem >> 2, ks = rem & 3;
    int n = nt * 16 + (lane & 15);
    int kb = ks * 32 + (lane >> 4) * 8;
    ushort8 v;
#pragma unroll
    for (int r = 0; r < 8; ++r) {
      union { __bf16 b; unsigned short u; } c;
      c.b = (__bf16)W1[(layer * 128 + kb + r) * 128 + n];
      v[r] = c.u;
    }
    *reinterpret_cast<ushort8*>(wp1 + ((size_t)g * 64 + lane) * 8) = v;
  } else if (g < 144) {                           // W2: 3*4*4 groups, k permuted
    int g2 = g - 96;
    int layer = g2 >> 4, rem = g2 & 15, nt = rem >> 2, ks = rem & 3;
    int n = nt * 16 + (lane & 15);
    int kb = ks * 32 + (lane >> 4) * 8;
    ushort8 v;
#pragma unroll
    for (int r = 0; r < 8; ++r) {
      union { __bf16 b; unsigned short u; } c;
      c.b = (__bf16)W2[(layer * 128 + p2l(kb + r)) * 64 + n];
      v[r] = c.u;
    }
    *reinterpret_cast<ushort8*>(wp2 + ((size_t)g2 * 64 + lane) * 8) = v;
  } else if (g < 150) {                           // gamma/beta permuted tables
    int g2 = g - 144;                             // 0..5
    int layer = g2 >> 1, param = g2 & 1;
    const float* src = (param == 0 ? gamma : beta) + layer * 128;
    float* dst = gbt + (layer * 2 + param) * 128;
    int p0 = lane * 2;
    dst[p0] = src[p2l(p0)];
    dst[p0 + 1] = src[p2l(p0 + 1)];
  }
}

// ---------------------------------------------------------------------------
// Fused depth-3 MLP stack, one workgroup (4 waves) per batch row b.
// xbuf: bf16 [64][128], XOR-swizzled (byte ^= (row&7)<<4), MFMA A operand.
// hbuf: bf16 [64][136], hidden-dim stored in PHYS (pair-packed) order.
// ---------------------------------------------------------------------------
__global__ __launch_bounds__(256, 4) void fused_mlp(
    const float* __restrict__ hidden,
    const float* __restrict__ b1,
    const float* __restrict__ b2,
    const unsigned short* __restrict__ wp1u,
    const unsigned short* __restrict__ wp2u,
    const float* __restrict__ gbt,
    float* __restrict__ out) {
  __shared__ __align__(16) unsigned short xbuf[NL * NH];   // 16384 B
  __shared__ __align__(16) unsigned hbufu[NL * 68];        // 17408 B (bf16 ld=136)
  __shared__ float x2buf[64];

  const int tid = threadIdx.x;
  const int wave = tid >> 6, lane = tid & 63;
  const int ci = lane & 15, lg = lane >> 4;
  char* xc = reinterpret_cast<char*>(xbuf);
  char* hc = reinterpret_cast<char*>(hbufu);

  // ---- stage 0: load hidden[b] (f32) -> xbuf (bf16, swizzled) ----
  const float* src = hidden + (size_t)blockIdx.x * (NL * NH);
#pragma unroll
  for (int i = 0; i < 4; ++i) {
    int f = i * 256 + tid;          // 8-elem chunk id, 0..1023
    int row = f >> 4;
    int cb = (f & 15) * 16;         // byte column
    const float4* p = reinterpret_cast<const float4*>(src + f * 8);
    float4 a = p[0], bq = p[1];
    bf16x8 v;
    v[0] = (__bf16)a.x;  v[1] = (__bf16)a.y;  v[2] = (__bf16)a.z;  v[3] = (__bf16)a.w;
    v[4] = (__bf16)bq.x; v[5] = (__bf16)bq.y; v[6] = (__bf16)bq.z; v[7] = (__bf16)bq.w;
    *reinterpret_cast<bf16x8*>(xc + row * 256 + (cb ^ ((row & 7) << 4))) = v;
  }
  __syncthreads();

  for (int layer = 0; layer < 3; ++layer) {
    // ========== GEMM1: h = x @ W1 + b1  (wave -> logical cols [wave*32,+32)) =
    f32x4 acc[4][2];
#pragma unroll
    for (int mt = 0; mt < 4; ++mt) {
      acc[mt][0] = f32x4{0.f, 0.f, 0.f, 0.f};
      acc[mt][1] = f32x4{0.f, 0.f, 0.f, 0.f};
    }
    const unsigned short* wl1 = wp1u + (size_t)layer * 16384;
#pragma unroll
    for (int ks = 0; ks < 4; ++ks) {
      bf16x8 bf0 = *reinterpret_cast<const bf16x8*>(
          wl1 + (((wave * 2 + 0) * 4 + ks) * 64 + lane) * 8);
      bf16x8 bf1 = *reinterpret_cast<const bf16x8*>(
          wl1 + (((wave * 2 + 1) * 4 + ks) * 64 + lane) * 8);
#pragma unroll
      for (int mt = 0; mt < 4; ++mt) {
        int row = mt * 16 + ci;
        int cb = ks * 64 + lg * 16;
        bf16x8 af = *reinterpret_cast<const bf16x8*>(
            xc + row * 256 + (cb ^ ((row & 7) << 4)));
        acc[mt][0] = __builtin_amdgcn_mfma_f32_16x16x32_bf16(af, bf0, acc[mt][0], 0, 0, 0);
        acc[mt][1] = __builtin_amdgcn_mfma_f32_16x16x32_bf16(af, bf1, acc[mt][1], 0, 0, 0);
      }
    }
    // writeback: pair-pack (col c, c+16) -> one bf16x2 dword at PHYS position
    {
      float bv0 = b1[layer * 128 + wave * 32 + ci];
      float bv1 = b1[layer * 128 + wave * 32 + 16 + ci];
#pragma unroll
      for (int mt = 0; mt < 4; ++mt)
#pragma unroll
        for (int r = 0; r < 4; ++r) {
          int row = mt * 16 + lg * 4 + r;
          hbufu[row * 68 + wave * 16 + ci] =
              pk2(acc[mt][0][r] + bv0, acc[mt][1][r] + bv1);
        }
    }
    __syncthreads();

    // ========== LayerNorm + ReLU: 4 rows in parallel per wave ===============
    {
      const float* gt = gbt + layer * 256;       // gamma~ (phys order)
      const float* bt = gt + 128;                // beta~
      float4 g0 = *reinterpret_cast<const float4*>(gt + ci * 8);
      float4 g1 = *reinterpret_cast<const float4*>(gt + ci * 8 + 4);
      float4 t0 = *reinterpret_cast<const float4*>(bt + ci * 8);
      float4 t1 = *reinterpret_cast<const float4*>(bt + ci * 8 + 4);
#pragma unroll
      for (int rr = 0; rr < 4; ++rr) {
        int row = wave * 16 + rr * 4 + lg;
        bf16x8 hv = *reinterpret_cast<const bf16x8*>(hc + row * 272 + ci * 16);
        float v[8];
#pragma unroll
        for (int j = 0; j < 8; ++j) v[j] = (float)hv[j];
        float s = 0.f, sq = 0.f;
#pragma unroll
        for (int j = 0; j < 8; ++j) { s += v[j]; sq += v[j] * v[j]; }
#pragma unroll
        for (int o = 1; o < 16; o <<= 1) {
          s += __shfl_xor(s, o);
          sq += __shfl_xor(sq, o);
        }
        float mu = s * (1.f / 128.f);
        float var = sq * (1.f / 128.f) - mu * mu;
        float rs = rsqrtf(var + 1e-5f);
        float ga[8] = {g0.x, g0.y, g0.z, g0.w, g1.x, g1.y, g1.z, g1.w};
        float be[8] = {t0.x, t0.y, t0.z, t0.w, t1.x, t1.y, t1.z, t1.w};
        bf16x8 y;
#pragma unroll
        for (int j = 0; j < 8; ++j) {
          float a = rs * ga[j];
          y[j] = (__bf16)fmaxf(fmaf(v[j], a, be[j] - mu * a), 0.f);
        }
        *reinterpret_cast<bf16x8*>(
            xc + row * 256 + ((ci * 16) ^ ((row & 7) << 4))) = y;
      }
    }
    __syncthreads();

    // ========== GEMM2: x1 = h @ W2 + b2 (wave -> cols [wave*16,+16)) ========
    f32x4 acc2[4];
#pragma unroll
    for (int mt = 0; mt < 4; ++mt) acc2[mt] = f32x4{0.f, 0.f, 0.f, 0.f};
    const unsigned short* wl2 = wp2u + (size_t)layer * 8192;
#pragma unroll
    for (int ks = 0; ks < 4; ++ks) {
      bf16x8 bfr = *reinterpret_cast<const bf16x8*>(
          wl2 + ((wave * 4 + ks) * 64 + lane) * 8);
#pragma unroll
      for (int mt = 0; mt < 4; ++mt) {
        int row = mt * 16 + ci;
        int cb = ks * 64 + lg * 16;
        bf16x8 af = *reinterpret_cast<const bf16x8*>(
            xc + row * 256 + (cb ^ ((row & 7) << 4)));
        acc2[mt] = __builtin_amdgcn_mfma_f32_16x16x32_bf16(af, bfr, acc2[mt], 0, 0, 0);
      }
    }
    float b2v = b2[layer * 64 + wave * 16 + ci];

    // in-register max-pool over all 64 rows (union of lane groups via shfl)
    {
      float m = -3.0e38f;
#pragma unroll
      for (int mt = 0; mt < 4; ++mt)
#pragma unroll
        for (int r = 0; r < 4; ++r) m = fmaxf(m, acc2[mt][r]);
      m = fmaxf(m, __shfl_xor(m, 16));
      m = fmaxf(m, __shfl_xor(m, 32));
      if (lane < 16) x2buf[wave * 16 + lane] = m + b2v;
    }

    if (layer < 2) {
      // x1 -> xbuf cols [0,64): pair-pack adjacent cols via shfl_xor(1)
#pragma unroll
      for (int mt = 0; mt < 4; ++mt)
#pragma unroll
        for (int r = 0; r < 4; ++r) {
          float vv = acc2[mt][r] + b2v;
          float pv = __shfl_xor(vv, 1);
          if ((ci & 1) == 0) {
            int row = mt * 16 + lg * 4 + r;
            int col = wave * 16 + ci;
            *reinterpret_cast<unsigned*>(
                xc + row * 256 + ((col * 2) ^ ((row & 7) << 4))) = pk2(vv, pv);
          }
        }
      __syncthreads();
      // broadcast x2 -> xbuf cols [64,128) for all rows
      {
        int row = tid >> 2, jq = tid & 3;
#pragma unroll
        for (int h = 0; h < 2; ++h) {
          float4 xa = *reinterpret_cast<const float4*>(x2buf + jq * 16 + h * 8);
          float4 xb = *reinterpret_cast<const float4*>(x2buf + jq * 16 + h * 8 + 4);
          bf16x8 v;
          v[0] = (__bf16)xa.x; v[1] = (__bf16)xa.y; v[2] = (__bf16)xa.z; v[3] = (__bf16)xa.w;
          v[4] = (__bf16)xb.x; v[5] = (__bf16)xb.y; v[6] = (__bf16)xb.z; v[7] = (__bf16)xb.w;
          *reinterpret_cast<bf16x8*>(
              xc + row * 256 + ((128 + jq * 32 + h * 16) ^ ((row & 7) << 4))) = v;
        }
      }
      __syncthreads();
    } else {
      __syncthreads();
      // final output (f32): out[b] = [x2_3, x2_3]
      if (tid < 128) {
        size_t o = (size_t)blockIdx.x * 128;
        out[o + tid] = x2buf[tid & 63];
      }
    }
  }
}

extern "C" void kernel_launch(void* const* d_in, const int* in_sizes, int n_in,
                              void* d_out, int out_size, void* d_ws, size_t ws_size,
                              hipStream_t stream) {
  const float* hidden = (const float*)d_in[0];
  const float* W1 = (const float*)d_in[1];
  const float* b1 = (const float*)d_in[2];
  const float* gamma = (const float*)d_in[3];
  const float* beta = (const float*)d_in[4];
  const float* W2 = (const float*)d_in[5];
  const float* b2 = (const float*)d_in[6];
  (void)in_sizes; (void)n_in; (void)out_size; (void)ws_size;

  unsigned short* wp1 = (unsigned short*)d_ws;          // 49152 ushorts
  unsigned short* wp2 = wp1 + 3 * 8 * 4 * 64 * 8;       // 24576 ushorts
  float* gbt = (float*)(wp2 + 3 * 4 * 4 * 64 * 8);      // 768 f32
  float* out = (float*)d_out;

  repack_w<<<38, 256, 0, stream>>>(W1, W2, gamma, beta, wp1, wp2, gbt);
  fused_mlp<<<NB, 256, 0, stream>>>(hidden, b1, b2, wp1, wp2, gbt, out);
}